// Round 11
// baseline (422.027 us; speedup 1.0000x reference)
//
#include <hip/hip_runtime.h>
#include <stdint.h>

// GraphVertModel: B=32, M=512, F_N=64, D=128, GS=4, L=8
// Round 11: occupancy rewrite of k_fused. B (Mh panel) and W read DIRECTLY
// from global (L2-resident per XCD: same-b blocks pinned to one XCD), so LDS
// = A-staging 3x8KB + f32 reduction 32KB (overlapping) + hbL 8KB = 40 KB.
// 32-row blocks, grid 512, __launch_bounds__(512,4) -> 2 blocks/CU: sibling
// block's waves hide the per-K-step barrier/vmcnt stalls (m97 mechanism).
// Reduction in two col-half passes. k_conv kept as round-8 (G path pinned
// ~2-2.7 TB/s across 4 structures; stop fighting it).
// Pipeline: k_convW -> k_conv(G) -> k_pre -> k_fused x8.
// ws: Gh 64M @0 | Mh0 16M @64M | Mh1 16M @80M | h 8M @96M | W0T @104M |
//     WlT @104M+64K

#define B_  32
#define M_  512
#define FN_ 64
#define D_  128
#define GS_ 4
#define L_  8

typedef __attribute__((ext_vector_type(8))) short short8;
typedef __attribute__((ext_vector_type(4))) float f32x4;
typedef unsigned short us;

__device__ __forceinline__ us f2bf(float f) {
  union { float f; unsigned int u; } v; v.f = f;
  return (us)((v.u + 0x7FFFu + ((v.u >> 16) & 1u)) >> 16);  // RTNE
}

__device__ __forceinline__ void gl16(const void* g, void* l) {
  __builtin_amdgcn_global_load_lds((const __attribute__((address_space(1))) void*)g,
                                   (__attribute__((address_space(3))) void*)l, 16, 0, 0);
}

// ---- G: fp32 -> bf16, streaming (plain coalesced float4 loads) ------------
__global__ void k_conv(const float4* __restrict__ src, ushort4* __restrict__ dst, int n4) {
  int i = blockIdx.x * blockDim.x + threadIdx.x;
  const int st = gridDim.x * blockDim.x;
  for (; i < n4; i += st) {
    float4 v = src[i];
    ushort4 o;
    o.x = f2bf(v.x); o.y = f2bf(v.y); o.z = f2bf(v.z); o.w = f2bf(v.w);
    dst[i] = o;
  }
}

// ---- weights: convert + transpose ([g][c][p] -> [g][p][c]) ----------------
__global__ void k_convW(const float* __restrict__ W0, const float* __restrict__ Wl,
                        us* __restrict__ W0T, us* __restrict__ WlT) {
  int i = blockIdx.x * blockDim.x + threadIdx.x;
  const int n0 = GS_ * FN_ * D_;
  if (i < n0) {
    int g = i / (FN_ * D_), r = i % (FN_ * D_), c = r / D_, p = r % D_;
    W0T[((size_t)g * D_ + p) * FN_ + c] = f2bf(W0[i]);
  } else {
    int j = i - n0;
    if (j < 7 * GS_ * D_ * D_) {
      int l = j / (GS_ * D_ * D_), r = j % (GS_ * D_ * D_);
      int g = r / (D_ * D_), r2 = r % (D_ * D_), c = r2 / D_, p = r2 % D_;
      WlT[(((size_t)l * GS_ + g) * D_ + p) * D_ + c] = f2bf(Wl[j]);
    }
  }
}

// ---- stage A: multi[g][n(my 32)][p] = hbL @ W + bias -> Mw ([p][n] bf16) --
// W read directly from global (L2-resident, shared by all 512 blocks).
template<int NKA, int CC>
__device__ __forceinline__ void stageA(const us* __restrict__ Wt,
                                       const float* __restrict__ bias,
                                       us* __restrict__ Mw, const us* hbL,
                                       int g, int hf, int lr, int kq, int b, int mt) {
  const int cm = (CC == 64) ? 7 : 15;
  const us* Wg = Wt + (size_t)g * D_ * CC + (size_t)(hf * 64) * CC;
  f32x4 acc[2][4];
#pragma unroll
  for (int i = 0; i < 2; ++i)
#pragma unroll
    for (int j = 0; j < 4; ++j) acc[i][j] = (f32x4){0.f, 0.f, 0.f, 0.f};

#define LDW(WR, ks) do { _Pragma("unroll") \
    for (int j_ = 0; j_ < 4; ++j_) \
      WR[j_] = *(const short8*)(Wg + (size_t)(j_ * 16 + lr) * CC + (ks) * 32 + kq * 8); \
  } while (0)

  short8 wA[4], wB[4];
  LDW(wA, 0);
#pragma unroll
  for (int ks = 0; ks < NKA; ++ks) {
    if (ks + 1 < NKA) { if (ks & 1) LDW(wA, ks + 1); else LDW(wB, ks + 1); }
    short8 af[2];
#pragma unroll
    for (int i = 0; i < 2; ++i)
      af[i] = *(const short8*)&hbL[(i * 16 + lr) * 128 + (((ks * 4 + kq) ^ (lr & cm)) << 3)];
    const short8* wf = (ks & 1) ? wB : wA;
#pragma unroll
    for (int i = 0; i < 2; ++i)
#pragma unroll
      for (int j = 0; j < 4; ++j)
        acc[i][j] = __builtin_amdgcn_mfma_f32_16x16x32_bf16(af[i], wf[j], acc[i][j], 0, 0, 0);
  }
#undef LDW

#pragma unroll
  for (int j = 0; j < 4; ++j) {
    const int p = hf * 64 + j * 16 + lr;
    const float bv = bias[g * D_ + p];
    us* op = Mw + ((size_t)(b * GS_ + g) * D_ + p) * M_;
#pragma unroll
    for (int i = 0; i < 2; ++i) {
      const int n0 = mt * 32 + i * 16 + kq * 4;
      f32x4 v = acc[i][j];
      ushort4 o;
      o.x = f2bf(v[0] + bv); o.y = f2bf(v[1] + bv);
      o.z = f2bf(v[2] + bv); o.w = f2bf(v[3] + bv);
      *(ushort4*)(op + n0) = o;
    }
  }
}

// ---- k_pre: x->hbL + stage A(0) -> Mh0 ------------------------------------
__launch_bounds__(512, 4)
__global__ void k_pre(const float* __restrict__ x, const us* __restrict__ W0T,
                      const float* __restrict__ b0, us* __restrict__ Mh0) {
  __shared__ __align__(16) us hbL[4096];  // [32][128] swizzled, 64 cols used
  const int bid = blockIdx.x;
  const int swz = (bid & 7) * 64 + (bid >> 3);
  const int b = swz >> 4, mt = swz & 15;
  const int t = threadIdx.x;
  const int w = t >> 6, g = w >> 1, hf = w & 1;
  const int lane = t & 63, lr = lane & 15, kq = lane >> 4;
  {
    const int row = t >> 4, c8 = t & 15;
    if (c8 < 8) {
      const float* xs = x + ((size_t)b * M_ + mt * 32 + row) * FN_ + c8 * 8;
      float4 v0 = *(const float4*)xs, v1 = *(const float4*)(xs + 4);
      ushort4 o0, o1;
      o0.x = f2bf(v0.x); o0.y = f2bf(v0.y); o0.z = f2bf(v0.z); o0.w = f2bf(v0.w);
      o1.x = f2bf(v1.x); o1.y = f2bf(v1.y); o1.z = f2bf(v1.z); o1.w = f2bf(v1.w);
      us* dp = hbL + row * 128 + ((c8 ^ (row & 7)) << 3);
      *(ushort4*)dp = o0; *(ushort4*)(dp + 4) = o1;
    }
  }
  __syncthreads();
  stageA<FN_ / 32, FN_>(W0T, b0, Mh0, hbL, g, hf, lr, kq, b, mt);
}

// ---- fused: stage B + relu + channel-max + residual + stage A(l+1) --------
// 32-row block, 8 waves (g, col-half), 40 KB LDS, 2 blocks/CU.
template<int FIRST, int LAST>
__launch_bounds__(512, 4)
__global__ void k_fused(const us* __restrict__ Gh, const us* __restrict__ Min,
                        us* __restrict__ Mout,
                        const us* __restrict__ WT, const float* __restrict__ bias,
                        float* __restrict__ h,
                        const float* __restrict__ Wout, const float* __restrict__ bout,
                        float* __restrict__ out) {
  __shared__ __align__(16) us sm[20480];  // 40 KB: A-stage 3x8KB ⊂ red 32KB | hbL 8KB
  us* Ast = sm;                           // buffer i at i*4096 us; per g 1024 us
  float* red = (float*)sm;                // [4][32][64] f32, chunk-swizzled
  us* hbL = sm + 16384;

  const int bid = blockIdx.x;
  const int swz = (bid & 7) * 64 + (bid >> 3);  // same-b blocks on one XCD
  const int b = swz >> 4, mt = swz & 15;

  const int t = threadIdx.x;
  const int w = t >> 6, g = w >> 1, hf = w & 1;
  const int lane = t & 63, lr = lane & 15, kq = lane >> 4;
  const int srow = lane >> 2;
  const int scol = ((lane & 3) ^ ((lane >> 3) & 3)) * 8;  // pre-swz source chunk
  const int kk = (kq ^ ((lr >> 1) & 3)) * 8;              // swz read chunk

  const us* AgB = Gh + ((size_t)(b * GS_ + g) * M_ + mt * 32) * M_;
  const us* Bg  = Min + (size_t)(b * GS_ + g) * D_ * M_;

#define STA(bufi, ks) \
    gl16(AgB + (size_t)(hf * 16 + srow) * M_ + (ks) * 32 + scol, \
         Ast + (bufi) * 4096 + g * 1024 + hf * 512 + lane * 8)

#define LDB(BR, ks) do { _Pragma("unroll") \
    for (int j_ = 0; j_ < 4; ++j_) \
      BR[j_] = *(const short8*)(Bg + (size_t)(hf * 64 + j_ * 16 + lr) * M_ + (ks) * 32 + kq * 8); \
  } while (0)

  f32x4 acc[2][4];
#pragma unroll
  for (int i = 0; i < 2; ++i)
#pragma unroll
    for (int j = 0; j < 4; ++j) acc[i][j] = (f32x4){0.f, 0.f, 0.f, 0.f};

  short8 bfA[4], bfB[4];
  STA(0, 0); STA(1, 1); LDB(bfA, 0);

#pragma unroll
  for (int ks = 0; ks < 16; ++ks) {
    // A-gate: my A(ks) gl16 complete (counts: after A(ks) come B(ks-1..ks), A(ks+1))
    if (ks == 0)      asm volatile("s_waitcnt vmcnt(5)" ::: "memory");
    else if (ks < 15) asm volatile("s_waitcnt vmcnt(9)" ::: "memory");
    else              asm volatile("s_waitcnt vmcnt(8)" ::: "memory");
    __builtin_amdgcn_s_barrier();   // both waves of pair have A(ks) landed
    __builtin_amdgcn_sched_barrier(0);
    const us* sa = Ast + (ks % 3) * 4096 + g * 1024;
    short8 af[2];
#pragma unroll
    for (int i = 0; i < 2; ++i)
      af[i] = *(const short8*)&sa[i * 512 + lr * 32 + kk];
    if (ks + 2 < 16) STA((ks + 2) % 3, ks + 2);
    if (ks + 1 < 16) { if (ks & 1) LDB(bfA, ks + 1); else LDB(bfB, ks + 1); }
    asm volatile("s_waitcnt lgkmcnt(0)" ::: "memory");
    __builtin_amdgcn_sched_barrier(0);
    const short8* bf = (ks & 1) ? bfB : bfA;   // compiler auto-gates bf vmcnt
#pragma unroll
    for (int i = 0; i < 2; ++i)
#pragma unroll
      for (int j = 0; j < 4; ++j)
        acc[i][j] = __builtin_amdgcn_mfma_f32_16x16x32_bf16(af[i], bf[j], acc[i][j], 0, 0, 0);
  }
#undef STA
#undef LDB

  // ---- two col-half passes: relu + channel-max + residual -----------------
  float sdot = 0.f;
  const int row_r = t >> 4;       // 0..31
  const int c4 = t & 15;          // 4-f32 chunk within the 64-col half
#pragma unroll
  for (int p = 0; p < 2; ++p) {
    __builtin_amdgcn_s_barrier();  // K-loop ds_reads / prev-pass reads done
    if (hf == p) {                 // writers: waves owning this col-half
#pragma unroll
      for (int i = 0; i < 2; ++i)
#pragma unroll
        for (int j = 0; j < 4; ++j) {
          const int colL = j * 16 + lr;
          const int ch = colL >> 2, cw = colL & 3;
#pragma unroll
          for (int cc = 0; cc < 4; ++cc) {
            const int row = i * 16 + kq * 4 + cc;
            red[g * 2048 + row * 64 + ((ch ^ (row & 15)) << 2) + cw] =
                fmaxf(acc[i][j][cc], 0.f);
          }
        }
    }
    __builtin_amdgcn_s_barrier();
    // reduce: thread -> (row_r, cols p*64 + c4*4 .. +4)
    const int cs = (c4 ^ (row_r & 15)) << 2;
    const float* rp = red + row_r * 64 + cs;
    f32x4 v = *(const f32x4*)rp;
#pragma unroll
    for (int gg = 1; gg < 4; ++gg) {
      f32x4 u = *(const f32x4*)(rp + gg * 2048);
      v[0] = fmaxf(v[0], u[0]); v[1] = fmaxf(v[1], u[1]);
      v[2] = fmaxf(v[2], u[2]); v[3] = fmaxf(v[3], u[3]);
    }
    const size_t ho = ((size_t)b * M_ + mt * 32 + row_r) * D_ + p * 64 + c4 * 4;
    float4* hp = (float4*)(h + ho);
    if (!FIRST) {
      float4 hv = *hp;
      v[0] += hv.x; v[1] += hv.y; v[2] += hv.z; v[3] += hv.w;
    }
    if constexpr (!LAST) {
      *hp = (float4){v[0], v[1], v[2], v[3]};
      ushort4 o;
      o.x = f2bf(v[0]); o.y = f2bf(v[1]); o.z = f2bf(v[2]); o.w = f2bf(v[3]);
      us* dp = hbL + row_r * 128 + ((((c4 >> 1) + 8 * p) ^ (row_r & 15)) << 3) + (c4 & 1) * 4;
      *(ushort4*)dp = o;
    } else {
      const float4 wv = *(const float4*)(Wout + p * 64 + c4 * 4);
      sdot += v[0] * wv.x + v[1] * wv.y + v[2] * wv.z + v[3] * wv.w;
    }
  }

  if constexpr (!LAST) {
    __builtin_amdgcn_s_barrier();  // hbL fully written before stage A reads
    stageA<D_ / 32, D_>(WT, bias, Mout, hbL, g, hf, lr, kq, b, mt);
  } else {
    sdot += __shfl_xor(sdot, 1);
    sdot += __shfl_xor(sdot, 2);
    sdot += __shfl_xor(sdot, 4);
    sdot += __shfl_xor(sdot, 8);
    if ((t & 15) == 0) out[(size_t)b * M_ + mt * 32 + row_r] = sdot + bout[0];
  }
}

extern "C" void kernel_launch(void* const* d_in, const int* in_sizes, int n_in,
                              void* d_out, int out_size, void* d_ws, size_t ws_size,
                              hipStream_t stream) {
  const float* G    = (const float*)d_in[0];
  const float* x    = (const float*)d_in[1];
  const float* W0   = (const float*)d_in[2];
  const float* b0   = (const float*)d_in[3];
  const float* Wl   = (const float*)d_in[4];
  const float* bl   = (const float*)d_in[5];
  const float* Wout = (const float*)d_in[6];
  const float* bout = (const float*)d_in[7];

  char* ws = (char*)d_ws;
  us*   Gh  = (us*)(ws);
  us*   Mh0 = (us*)(ws + 67108864);
  us*   Mh1 = (us*)(ws + 83886080);
  float* h  = (float*)(ws + 100663296);
  us*   W0T = (us*)(ws + 109051904);
  us*   WlT = (us*)(ws + 109051904 + 65536);
  float* out = (float*)d_out;

  k_convW<<<1920, 256, 0, stream>>>(W0, Wl, W0T, WlT);
  k_conv<<<2048, 256, 0, stream>>>((const float4*)G, (ushort4*)Gh, (B_ * GS_ * M_ * M_) / 4);
  k_pre<<<512, 512, 0, stream>>>(x, W0T, b0, Mh0);

  // fused(l): stage B reads Mh[l&1]; stage A writes Mh[(l+1)&1] with Wl[l]
  k_fused<1, 0><<<512, 512, 0, stream>>>(Gh, Mh0, Mh1,
      WlT + (size_t)0 * GS_ * D_ * D_, bl + (size_t)0 * GS_ * D_,
      h, Wout, bout, out);
  for (int l = 1; l < L_ - 1; ++l) {
    const us* Min = (l & 1) ? Mh1 : Mh0;
    us* Mout      = (l & 1) ? Mh0 : Mh1;
    k_fused<0, 0><<<512, 512, 0, stream>>>(Gh, Min, Mout,
        WlT + (size_t)l * GS_ * D_ * D_, bl + (size_t)l * GS_ * D_,
        h, Wout, bout, out);
  }
  k_fused<0, 1><<<512, 512, 0, stream>>>(Gh, (L_ - 1) & 1 ? Mh1 : Mh0, nullptr,
      nullptr, nullptr, h, Wout, bout, out);
}